// Round 15
// baseline (595.305 us; speedup 1.0000x reference)
//
#include <hip/hip_runtime.h>

#define KDIM 8192
#define NDIM 16384
#define BDIM 16
#define NBLK 8                        // KDIM/1024 scale blocks per row
#define TN 8                          // output rows per wave
#define WAVES 8                       // 512-thread block
#define ROWS_PER_BLOCK (WAVES * TN)   // 64
#define KSPLIT 8
#define SLICE (KDIM / KSPLIT)         // 1024 = exactly one scale block
#define KC 256                        // k per chunk (64 lanes * 4)
#define NCHUNK (SLICE / KC)           // 4

// global->LDS direct copy, 16B/lane: LDS dest wave-uniform, global src per-lane.
__device__ __forceinline__ void gload_lds16(const float* g, float* l) {
    __builtin_amdgcn_global_load_lds(
        (const __attribute__((address_space(1))) unsigned int*)(uintptr_t)g,
        (__attribute__((address_space(3))) unsigned int*)(uintptr_t)l,
        16, 0, 0);
}

// Persistent-x K-split partial GEMM (round-13 theory, compile fix: macro
// param renamed WBUF -- a param named `w` got substituted into `xv.w`).
// Binder analysis (R7/R10/R13 plateau ~140us): combined vmem traffic
// (W 512MB + x re-staged 256MB) ran at ~9 B/cyc/CU = ~90% of the per-CU
// vmem ceiling (m13 ~10B/cyc/CU). Fix = cut x traffic: stage the x-slice
// ONCE per block (64KB LDS, 64 W-rows amortize it), then a BARRIER-FREE
// W-streaming K-loop (reg dbuf, sched_barrier-pinned, counted vmcnt).
// x traffic: 256MB -> 128MB; total ~648MB -> ~105us at path ceiling.
// launch_bounds(512), NO min-waves arg (measured: min-waves caps VGPR at
// 256/w and spills; bare bounds -> live-set-driven, no spill).
__global__ __launch_bounds__(512) void int8lin_partial(
    const float* __restrict__ x,
    const int* __restrict__ qw,
    const float* __restrict__ scales,
    float* __restrict__ part)         // [KSPLIT][16][NDIM]
{
    __shared__ float xs[BDIM][SLICE];   // 64 KB

    const int tid  = threadIdx.x;
    const int lane = tid & 63;
    const int wave = tid >> 6;          // 0..7
    const int s    = blockIdx.y;        // k-slice = scale block
    const int n0   = blockIdx.x * ROWS_PER_BLOCK + wave * TN;
    const int k0   = s * SLICE;
    const int kbase = lane * 4;

    // Scales first (oldest vmem ops -> retired by the counted wait below).
    float sc[TN];
#pragma unroll
    for (int j = 0; j < TN; ++j)
        sc[j] = scales[(size_t)(n0 + j) * NBLK + s];

    // Stage x slice: wave stages rows 2w,2w+1 (4 gload_lds each) = 8 vmem.
#pragma unroll
    for (int q = 0; q < 2; ++q) {
        const int r = wave * 2 + q;
#pragma unroll
        for (int p = 0; p < NCHUNK; ++p)
            gload_lds16(x + (size_t)r * KDIM + k0 + p * KC + kbase, &xs[r][p * KC]);
    }

    const int* wp = qw + (size_t)n0 * KDIM + k0 + kbase;

    int4 wA[TN], wB[TN];
#pragma unroll
    for (int j = 0; j < TN; ++j)            // 8 vmem, stay in flight across barrier
        wA[j] = *reinterpret_cast<const int4*>(wp + (size_t)j * KDIM);
    __builtin_amdgcn_sched_barrier(0);

    float acc[BDIM][TN];
#pragma unroll
    for (int i = 0; i < BDIM; ++i)
#pragma unroll
        for (int j = 0; j < TN; ++j) acc[i][j] = 0.f;

    // Counted wait: retire sc + x-stage; keep the 8 wA loads in flight.
    asm volatile("s_waitcnt vmcnt(8)" ::: "memory");
    __builtin_amdgcn_s_barrier();
    __builtin_amdgcn_sched_barrier(0);

#define LOADW(WBUF, c)                                                       \
    _Pragma("unroll")                                                        \
    for (int j = 0; j < TN; ++j)                                             \
        WBUF[j] = *reinterpret_cast<const int4*>(wp + (size_t)j * KDIM + (c) * KC);

#define COMPUTE(WBUF, c)                                                     \
    do {                                                                     \
        float wf[TN][4];                                                     \
        _Pragma("unroll")                                                    \
        for (int j = 0; j < TN; ++j) {                                       \
            wf[j][0] = (float)WBUF[j].x * sc[j];                             \
            wf[j][1] = (float)WBUF[j].y * sc[j];                             \
            wf[j][2] = (float)WBUF[j].z * sc[j];                             \
            wf[j][3] = (float)WBUF[j].w * sc[j];                             \
        }                                                                    \
        _Pragma("unroll")                                                    \
        for (int i = 0; i < BDIM; ++i) {                                     \
            const float4 xv = *reinterpret_cast<const float4*>(              \
                &xs[i][(c) * KC + kbase]);                                   \
            _Pragma("unroll")                                                \
            for (int j = 0; j < TN; ++j) {                                   \
                acc[i][j] = fmaf(xv.x, wf[j][0], acc[i][j]);                 \
                acc[i][j] = fmaf(xv.y, wf[j][1], acc[i][j]);                 \
                acc[i][j] = fmaf(xv.z, wf[j][2], acc[i][j]);                 \
                acc[i][j] = fmaf(xv.w, wf[j][3], acc[i][j]);                 \
            }                                                                \
        }                                                                    \
    } while (0)

    // Barrier-free K-loop over the slice's 4 chunks; W one chunk ahead.
#pragma unroll 1
    for (int c = 0; c < NCHUNK; c += 2) {
        LOADW(wB, c + 1);
        __builtin_amdgcn_sched_barrier(0);   // pin prefetch above compute (R12)
        COMPUTE(wA, c);
        if (c + 2 < NCHUNK) { LOADW(wA, c + 2); }
        __builtin_amdgcn_sched_barrier(0);
        COMPUTE(wB, c + 1);
    }
#undef LOADW
#undef COMPUTE

    // 64-lane butterfly reduction; lane 0 stores the wave's 16xTN partial tile.
#pragma unroll
    for (int i = 0; i < BDIM; ++i)
#pragma unroll
        for (int j = 0; j < TN; ++j) {
            float v = acc[i][j];
#pragma unroll
            for (int off = 32; off >= 1; off >>= 1) v += __shfl_xor(v, off, 64);
            acc[i][j] = v;
        }

    if (lane == 0) {
#pragma unroll
        for (int i = 0; i < BDIM; ++i)
#pragma unroll
            for (int j = 0; j < TN; ++j)
                part[((size_t)(s * BDIM + i) << 14) + (n0 + j)] = acc[i][j];
    }
}

// out[i][n] = sum_s part[s][i][n] + bias[n]
__global__ __launch_bounds__(256) void int8lin_reduce(
    const float* __restrict__ part,
    const float* __restrict__ bias,
    float* __restrict__ out)
{
    const int idx = blockIdx.x * 256 + threadIdx.x;   // i*NDIM + n
    const int n = idx & (NDIM - 1);
    const int i = idx >> 14;
    float v = bias[n];
#pragma unroll
    for (int s = 0; s < KSPLIT; ++s)
        v += part[((size_t)(s * BDIM + i) << 14) + n];
    out[idx] = v;
}

// Safety-net fallback (no workspace): lane-per-row direct, slow but correct.
__global__ __launch_bounds__(256) void int8lin_direct(
    const float* __restrict__ x, const int* __restrict__ qw,
    const float* __restrict__ scales, const float* __restrict__ bias,
    float* __restrict__ out)
{
    const int n = blockIdx.x * 256 + threadIdx.x;
    float acc[BDIM];
#pragma unroll
    for (int i = 0; i < BDIM; ++i) acc[i] = 0.f;
    const int* wp = qw + (size_t)n * KDIM;
    for (int kb = 0; kb < KDIM; kb += 1024) {
        const float s = scales[n * NBLK + (kb >> 10)];
        for (int kk = 0; kk < 1024; kk += 4) {
            const int4 wv = *reinterpret_cast<const int4*>(wp + kb + kk);
            const float w0 = (float)wv.x * s, w1 = (float)wv.y * s;
            const float w2 = (float)wv.z * s, w3 = (float)wv.w * s;
#pragma unroll
            for (int i = 0; i < BDIM; ++i) {
                const float4 xv = *reinterpret_cast<const float4*>(x + (size_t)i * KDIM + kb + kk);
                acc[i] = fmaf(xv.x, w0, fmaf(xv.y, w1, fmaf(xv.z, w2, fmaf(xv.w, w3, acc[i]))));
            }
        }
    }
    const float b = bias[n];
#pragma unroll
    for (int i = 0; i < BDIM; ++i) out[(size_t)i * NDIM + n] = acc[i] + b;
}

extern "C" void kernel_launch(void* const* d_in, const int* in_sizes, int n_in,
                              void* d_out, int out_size, void* d_ws, size_t ws_size,
                              hipStream_t stream) {
    const float* x      = (const float*)d_in[0];
    const int*   qw     = (const int*)d_in[1];
    const float* scales = (const float*)d_in[2];
    const float* bias   = (const float*)d_in[3];
    float*       out    = (float*)d_out;

    const size_t need = (size_t)KSPLIT * BDIM * NDIM * sizeof(float);   // 8 MB

    if (ws_size >= need) {
        float* part = (float*)d_ws;
        dim3 grid(NDIM / ROWS_PER_BLOCK, KSPLIT);   // (256, 8)
        int8lin_partial<<<grid, dim3(512), 0, stream>>>(x, qw, scales, part);
        int8lin_reduce<<<(BDIM * NDIM) / 256, 256, 0, stream>>>(part, bias, out);
    } else {
        int8lin_direct<<<NDIM / 256, 256, 0, stream>>>(x, qw, scales, bias, out);
    }
}